// Round 12
// baseline (298.527 us; speedup 1.0000x reference)
//
#include <hip/hip_runtime.h>
#include <stdint.h>

#define F 16
#define CDIM 320
#define DDIM 4096
#define NSEQ 8192
#define WPB 4
#define THREADS 256
#define NT 20
#define KS 10

typedef __attribute__((ext_vector_type(8))) short short8;
typedef __attribute__((ext_vector_type(4))) float f32x4;

__device__ __forceinline__ unsigned short f2bf(float f) {
    union { float f; uint32_t u; } v; v.f = f;
    uint32_t r = v.u + 0x7FFFu + ((v.u >> 16) & 1u);   // RTNE
    return (unsigned short)(r >> 16);
}
__device__ __forceinline__ float bf2f(unsigned short h) {
    union { uint32_t u; float f; } v; v.u = ((uint32_t)h) << 16;
    return v.f;
}
// XOR swizzle inside a [16][320] bf16 row-major tile (row stride 640 B).
// 16B chunks; chunk ^ (row&7) is a bijection per row -> disjoint regions
// stay disjoint under the swizzle.
__device__ __forceinline__ int swz(int row, int b) {
    return row * 640 + (b ^ ((row & 7) << 4));
}

// One-time: pack Wq/Wk/Wv/Wo (fp32 row-major [320][320]) into bf16 B-fragment
// order. Fragment (m, nt, ks) is a 1KB block: lane (g,lr) holds
// W[nt*16+lr][ks*32+g*8 .. +7]. Byte offset = ((m*NT+nt)*KS+ks)*1024 + lane*16.
__global__ __launch_bounds__(256)
void pack_weights_kernel(const float* __restrict__ Wq, const float* __restrict__ Wk,
                         const float* __restrict__ Wv, const float* __restrict__ Wo,
                         char* __restrict__ pk)
{
    const int t = blockIdx.x * 256 + threadIdx.x;
    if (t >= 4 * NT * KS * 64) return;
    const int lane = t & 63;
    const int rest = t >> 6;
    const int ks = rest % KS;
    const int nt = (rest / KS) % NT;
    const int m  = rest / (KS * NT);
    const float* W = (m == 0) ? Wq : (m == 1) ? Wk : (m == 2) ? Wv : Wo;
    const int g = lane >> 4, lr = lane & 15;
    const float* src = W + (size_t)(nt * 16 + lr) * CDIM + ks * 32 + g * 8;
    const f32x4 a = *(const f32x4*)src;
    const f32x4 b = *(const f32x4*)(src + 4);
    float vals[8] = {a[0], a[1], a[2], a[3], b[0], b[1], b[2], b[3]};
    short8 o;
#pragma unroll
    for (int j = 0; j < 8; ++j) o[j] = (short)f2bf(vals[j]);
    *(short8*)(pk + (size_t)t * 16) = o;
}

// EXACT R11 structure (clean: 108 VGPR, FETCH 105MB) + ONE change: a raw
// s_barrier (no vmcnt drain, unlike __syncthreads -- prefetch survives) at
// the top of every weight-tile iteration. Purpose: phase-lock the block's 4
// waves so they stream the same 20KB weight window together -> 1 L2 miss +
// 3 L1 hits instead of 4 independent L2 streams (6.7 GB -> ~1.7 GB L2
// demand). Scheduling-only: no data crosses these barriers.
__global__ __launch_bounds__(THREADS, 2)
void temporal_attn_kernel(const float* __restrict__ hs,
                          const char* __restrict__ wpk,
                          const float* __restrict__ bo,
                          float* __restrict__ out)
{
    extern __shared__ __align__(16) char smem[];
    const int tid  = threadIdx.x;
    const int lane = tid & 63;
    const int wave = tid >> 6;
    const int g    = lane >> 4;
    const int lr   = lane & 15;

    const int seq = blockIdx.x * WPB + wave;
    const int bi  = seq >> 12;
    const int di  = seq & (DDIM - 1);

    char* const kbuf = smem + wave * 20480;   // Q, then K, then attn-out
    char* const vbuf = kbuf + 10240;          // V
    const char* const wl = wpk + lane * 16;

    // ---- load x rows, add PE, convert to bf16 A-fragments ----
    const float* xrow = hs + ((size_t)(bi * F + lr) * DDIM + di) * CDIM;
    short8 axk[KS];
#pragma unroll
    for (int ks = 0; ks < KS; ++ks) {
        const int k0 = ks * 32 + g * 8;
        const f32x4 a = __builtin_nontemporal_load((const f32x4*)(xrow + k0));
        const f32x4 b = __builtin_nontemporal_load((const f32x4*)(xrow + k0 + 4));
        float xv[8] = {a[0], a[1], a[2], a[3], b[0], b[1], b[2], b[3]};
#pragma unroll
        for (int jj = 0; jj < 4; ++jj) {
            const float c0 = (float)(k0 + 2 * jj);
            const float dv = __expf(c0 * -0.028782313662425575f); // -ln(1e4)/320
            const float ang = (float)lr * dv;                      // pos = frame
            xv[2 * jj]     += __sinf(ang);
            xv[2 * jj + 1] += __cosf(ang);
        }
        short8 t;
#pragma unroll
        for (int j = 0; j < 8; ++j) t[j] = (short)f2bf(xv[j]);
        axk[ks] = t;
    }

    // ---- projection pass, ping-pong pipelined over 20 n-tiles ----
    // Raw s_barrier at iteration top phase-locks the 4 waves' load windows.
    auto proj = [&](int m, char* dst) {
        const char* base = wl + (size_t)(m * NT) * KS * 1024;
        short8 fa[KS], fb[KS];
#pragma unroll
        for (int ks = 0; ks < KS; ++ks)
            fa[ks] = *(const short8*)(base + (size_t)ks * 1024);
#pragma unroll 1
        for (int np = 0; np < 10; ++np) {
            __builtin_amdgcn_s_barrier();   // schedule alignment only
#pragma unroll
            for (int ks = 0; ks < KS; ++ks)
                fb[ks] = *(const short8*)(base + (size_t)((2 * np + 1) * KS + ks) * 1024);
            f32x4 a0l = {0.f, 0.f, 0.f, 0.f}, a0h = {0.f, 0.f, 0.f, 0.f};
#pragma unroll
            for (int k5 = 0; k5 < 5; ++k5) {
                a0l = __builtin_amdgcn_mfma_f32_16x16x32_bf16(axk[k5],     fa[k5],     a0l, 0, 0, 0);
                a0h = __builtin_amdgcn_mfma_f32_16x16x32_bf16(axk[k5 + 5], fa[k5 + 5], a0h, 0, 0, 0);
            }
            const f32x4 a0 = a0l + a0h;
            if (np < 9) {
#pragma unroll
                for (int ks = 0; ks < KS; ++ks)
                    fa[ks] = *(const short8*)(base + (size_t)((2 * np + 2) * KS + ks) * 1024);
            }
            f32x4 a1l = {0.f, 0.f, 0.f, 0.f}, a1h = {0.f, 0.f, 0.f, 0.f};
#pragma unroll
            for (int k5 = 0; k5 < 5; ++k5) {
                a1l = __builtin_amdgcn_mfma_f32_16x16x32_bf16(axk[k5],     fb[k5],     a1l, 0, 0, 0);
                a1h = __builtin_amdgcn_mfma_f32_16x16x32_bf16(axk[k5 + 5], fb[k5 + 5], a1h, 0, 0, 0);
            }
            const f32x4 a1 = a1l + a1h;
#pragma unroll
            for (int r = 0; r < 4; ++r) {
                const int row = g * 4 + r;
                *(short*)(dst + swz(row, (2 * np * 16 + lr) * 2))       = (short)f2bf(a0[r]);
                *(short*)(dst + swz(row, ((2 * np + 1) * 16 + lr) * 2)) = (short)f2bf(a1[r]);
            }
        }
    };

    proj(0, kbuf);                       // Q -> kbuf (transient)
    short8 qreg[2][5];                   // statically indexed everywhere
#pragma unroll
    for (int h2 = 0; h2 < 2; ++h2)
#pragma unroll
        for (int j5 = 0; j5 < 5; ++j5)
            qreg[h2][j5] = *(const short8*)(kbuf + swz(lr, (g + 4 * h2) * 80 + j5 * 16));
    proj(1, kbuf);                       // K overwrites Q
    proj(2, vbuf);                       // V

    // ---- causal attention; lane = (q-row = lr, head = g + 4*h2) ----
    const float scale = 0.15811388300841897f;  // 40^-0.5
#pragma unroll
    for (int h2 = 0; h2 < 2; ++h2) {
        const int cb = (g + 4 * h2) * 80;
        float s[F];
#pragma unroll
        for (int kk = 0; kk < F; ++kk) s[kk] = 0.f;
#pragma unroll
        for (int j5 = 0; j5 < 5; ++j5) {
            float qf[8];
#pragma unroll
            for (int j = 0; j < 8; ++j) qf[j] = bf2f((unsigned short)qreg[h2][j5][j]);
#pragma unroll
            for (int kk = 0; kk < F; ++kk) {
                short8 k8 = *(const short8*)(kbuf + swz(kk, cb + j5 * 16));
#pragma unroll
                for (int j = 0; j < 8; ++j) s[kk] += qf[j] * bf2f((unsigned short)k8[j]);
            }
        }
        float m = -1e30f;
#pragma unroll
        for (int kk = 0; kk < F; ++kk) {
            s[kk] = (kk <= lr) ? s[kk] * scale : -1e30f;
            m = fmaxf(m, s[kk]);
        }
        float sum = 0.f;
#pragma unroll
        for (int kk = 0; kk < F; ++kk) { s[kk] = __expf(s[kk] - m); sum += s[kk]; }
        const float inv = 1.f / sum;
#pragma unroll
        for (int kk = 0; kk < F; ++kk) s[kk] *= inv;

        // PV chunked: one 8-wide d-chunk at a time, packed straight to LDS
#pragma unroll
        for (int j5 = 0; j5 < 5; ++j5) {
            float a8[8];
#pragma unroll
            for (int j = 0; j < 8; ++j) a8[j] = 0.f;
#pragma unroll
            for (int kk = 0; kk < F; ++kk) {
                short8 v8 = *(const short8*)(vbuf + swz(kk, cb + j5 * 16));
#pragma unroll
                for (int j = 0; j < 8; ++j) a8[j] += s[kk] * bf2f((unsigned short)v8[j]);
            }
            short8 t;
#pragma unroll
            for (int j = 0; j < 8; ++j) t[j] = (short)f2bf(a8[j]);
            *(short8*)(kbuf + swz(lr, cb + j5 * 16)) = t;
        }
    }

    // ---- output projection: out = ao @ Wo.T + bo, pipelined + paired stores ----
    short8 aof[KS];
#pragma unroll
    for (int ks = 0; ks < KS; ++ks)
        aof[ks] = *(const short8*)(kbuf + swz(lr, ks * 64 + g * 16));

    {
        const char* base = wl + (size_t)(3 * NT) * KS * 1024;
        short8 fa[KS], fb[KS];
#pragma unroll
        for (int ks = 0; ks < KS; ++ks)
            fa[ks] = *(const short8*)(base + (size_t)ks * 1024);
#pragma unroll 1
        for (int np = 0; np < 10; ++np) {
            __builtin_amdgcn_s_barrier();   // schedule alignment only
#pragma unroll
            for (int ks = 0; ks < KS; ++ks)
                fb[ks] = *(const short8*)(base + (size_t)((2 * np + 1) * KS + ks) * 1024);
            f32x4 a0l = {0.f, 0.f, 0.f, 0.f}, a0h = {0.f, 0.f, 0.f, 0.f};
#pragma unroll
            for (int k5 = 0; k5 < 5; ++k5) {
                a0l = __builtin_amdgcn_mfma_f32_16x16x32_bf16(aof[k5],     fa[k5],     a0l, 0, 0, 0);
                a0h = __builtin_amdgcn_mfma_f32_16x16x32_bf16(aof[k5 + 5], fa[k5 + 5], a0h, 0, 0, 0);
            }
            const f32x4 a0 = a0l + a0h;
            if (np < 9) {
#pragma unroll
                for (int ks = 0; ks < KS; ++ks)
                    fa[ks] = *(const short8*)(base + (size_t)((2 * np + 2) * KS + ks) * 1024);
            }
            f32x4 a1l = {0.f, 0.f, 0.f, 0.f}, a1h = {0.f, 0.f, 0.f, 0.f};
#pragma unroll
            for (int k5 = 0; k5 < 5; ++k5) {
                a1l = __builtin_amdgcn_mfma_f32_16x16x32_bf16(aof[k5],     fb[k5],     a1l, 0, 0, 0);
                a1h = __builtin_amdgcn_mfma_f32_16x16x32_bf16(aof[k5 + 5], fb[k5 + 5], a1h, 0, 0, 0);
            }
            const f32x4 a1 = a1l + a1h;

            const int c0 = 2 * np * 16 + lr;
            const int c1 = c0 + 16;
            const float bias0 = bo[c0];
            const float bias1 = bo[c1];
            // rows are 1280B-aligned; pair np covers bytes [np*128, +128):
            // exactly one full 128B line per output row, no write amp.
#pragma unroll
            for (int r = 0; r < 4; ++r) {
                float* rowp = out + ((size_t)(bi * F + g * 4 + r) * DDIM + di) * CDIM;
                rowp[c0] = a0[r] + bias0;
                rowp[c1] = a1[r] + bias1;
            }
        }
    }
}

extern "C" void kernel_launch(void* const* d_in, const int* in_sizes, int n_in,
                              void* d_out, int out_size, void* d_ws, size_t ws_size,
                              hipStream_t stream) {
    const float* hs = (const float*)d_in[0];
    const float* Wq = (const float*)d_in[1];
    const float* Wk = (const float*)d_in[2];
    const float* Wv = (const float*)d_in[3];
    const float* Wo = (const float*)d_in[4];
    const float* bo = (const float*)d_in[5];
    float* out = (float*)d_out;
    char* wpk = (char*)d_ws;   // 4*200*1024 = 819200 B of packed bf16 weights

    pack_weights_kernel<<<dim3((4 * NT * KS * 64 + 255) / 256), dim3(256), 0, stream>>>(
        Wq, Wk, Wv, Wo, wpk);

    const int lds = WPB * 20480;   // 81920 B -> 2 blocks/CU (8 waves/CU)
    (void)hipFuncSetAttribute((const void*)temporal_attn_kernel,
                              hipFuncAttributeMaxDynamicSharedMemorySize, lds);
    temporal_attn_kernel<<<dim3(NSEQ / WPB), dim3(THREADS), lds, stream>>>(
        hs, wpk, bo, out);
}

// Round 13
// 252.536 us; speedup vs baseline: 1.1821x; 1.1821x over previous
//
#include <hip/hip_runtime.h>
#include <stdint.h>

#define F 16
#define CDIM 320
#define DDIM 4096
#define NSEQ 8192
#define WPB 4
#define THREADS 256
#define NT 20
#define KS 10

typedef __attribute__((ext_vector_type(8))) short short8;
typedef __attribute__((ext_vector_type(4))) float f32x4;
typedef __attribute__((ext_vector_type(2))) unsigned int uint2v;
typedef __attribute__((ext_vector_type(4))) unsigned int uint4v;

__device__ __forceinline__ unsigned short f2bf(float f) {
    union { float f; uint32_t u; } v; v.f = f;
    uint32_t r = v.u + 0x7FFFu + ((v.u >> 16) & 1u);   // RTNE
    return (unsigned short)(r >> 16);
}
// [16][320] bf16 tile swizzle, row stride 640 B, 16B chunks, chunk^(row&7)
// bijective per row and in-bounds (40 chunks = 5 groups of 8).
__device__ __forceinline__ int swz(int row, int b) {
    return row * 640 + (b ^ ((row & 7) << 4));
}

// One-time: pack Wq/Wk/Wv/Wo (fp32 row-major [320][320]) into bf16 B-fragment
// order. Fragment (m, nt, ks) is a 1KB block: lane (g,lr) holds
// W[nt*16+lr][ks*32+g*8 .. +7]. Byte offset = ((m*NT+nt)*KS+ks)*1024 + lane*16.
__global__ __launch_bounds__(256)
void pack_weights_kernel(const float* __restrict__ Wq, const float* __restrict__ Wk,
                         const float* __restrict__ Wv, const float* __restrict__ Wo,
                         char* __restrict__ pk)
{
    const int t = blockIdx.x * 256 + threadIdx.x;
    if (t >= 4 * NT * KS * 64) return;
    const int lane = t & 63;
    const int rest = t >> 6;
    const int ks = rest % KS;
    const int nt = (rest / KS) % NT;
    const int m  = rest / (KS * NT);
    const float* W = (m == 0) ? Wq : (m == 1) ? Wk : (m == 2) ? Wv : Wo;
    const int g = lane >> 4, lr = lane & 15;
    const float* src = W + (size_t)(nt * 16 + lr) * CDIM + ks * 32 + g * 8;
    const f32x4 a = *(const f32x4*)src;
    const f32x4 b = *(const f32x4*)(src + 4);
    float vals[8] = {a[0], a[1], a[2], a[3], b[0], b[1], b[2], b[3]};
    short8 o;
#pragma unroll
    for (int j = 0; j < 8; ++j) o[j] = (short)f2bf(vals[j]);
    *(short8*)(pk + (size_t)t * 16) = o;
}

// R11 chassis (clean 108 VGPR; barriers of R12 reverted: -6%) with attention
// moved from VALU to MFMA:
//  - scores: S^T = mfma(K, Q) (swapped operands; K/Q natural rows ARE the
//    A/B fragments). K-dim 40 = K=32 MFMA + zero-padded tail MFMA.
//  - softmax: 4 keys/lane, cross-group shfl_xor(16/32) reduces.
//  - PV: P reshuffled into the A-fragment (keys 16..31 zero-padded);
//    V stored TRANSPOSED (V'[col][key], [320][32B]) so B-frags are b128.
//  - pass order: Q->kbuf, K->vbuf, scores (p[8] in regs, 16 VGPR),
//    V'->kbuf (Q dead), PV -> attn-out -> vbuf (K dead), O-proj.
//    No qreg (-40 VGPR); only p crosses proj(2).
__global__ __launch_bounds__(THREADS, 2)
void temporal_attn_kernel(const float* __restrict__ hs,
                          const char* __restrict__ wpk,
                          const float* __restrict__ bo,
                          float* __restrict__ out)
{
    extern __shared__ __align__(16) char smem[];
    const int tid  = threadIdx.x;
    const int lane = tid & 63;
    const int wave = tid >> 6;
    const int g    = lane >> 4;
    const int lr   = lane & 15;

    const int seq = blockIdx.x * WPB + wave;
    const int bi  = seq >> 12;
    const int di  = seq & (DDIM - 1);

    char* const kbuf = smem + wave * 20480;   // Q, then V' (transposed)
    char* const vbuf = kbuf + 10240;          // K, then attn-out
    const char* const wl = wpk + lane * 16;

    // ---- load x rows, add PE, convert to bf16 A-fragments ----
    const float* xrow = hs + ((size_t)(bi * F + lr) * DDIM + di) * CDIM;
    short8 axk[KS];
#pragma unroll
    for (int ks = 0; ks < KS; ++ks) {
        const int k0 = ks * 32 + g * 8;
        const f32x4 a = __builtin_nontemporal_load((const f32x4*)(xrow + k0));
        const f32x4 b = __builtin_nontemporal_load((const f32x4*)(xrow + k0 + 4));
        float xv[8] = {a[0], a[1], a[2], a[3], b[0], b[1], b[2], b[3]};
#pragma unroll
        for (int jj = 0; jj < 4; ++jj) {
            const float c0 = (float)(k0 + 2 * jj);
            const float dv = __expf(c0 * -0.028782313662425575f); // -ln(1e4)/320
            const float ang = (float)lr * dv;                      // pos = frame
            xv[2 * jj]     += __sinf(ang);
            xv[2 * jj + 1] += __cosf(ang);
        }
        short8 t;
#pragma unroll
        for (int j = 0; j < 8; ++j) t[j] = (short)f2bf(xv[j]);
        axk[ks] = t;
    }

    // ---- projection pass, ping-pong pipelined, lo/hi chain split ----
    // mode 0: dst[row][col] standard swizzled [16][640B]
    // mode 1: transposed V' layout dst[col][key] = [320][32B] (no swizzle)
    auto proj = [&](int m, char* dst, int mode) {
        const char* base = wpk + lane * 16 + (size_t)(m * NT) * KS * 1024;
        short8 fa[KS], fb[KS];
#pragma unroll
        for (int ks = 0; ks < KS; ++ks)
            fa[ks] = *(const short8*)(base + (size_t)ks * 1024);
#pragma unroll 1
        for (int np = 0; np < 10; ++np) {
#pragma unroll
            for (int ks = 0; ks < KS; ++ks)
                fb[ks] = *(const short8*)(base + (size_t)((2 * np + 1) * KS + ks) * 1024);
            f32x4 a0l = {0.f, 0.f, 0.f, 0.f}, a0h = {0.f, 0.f, 0.f, 0.f};
#pragma unroll
            for (int k5 = 0; k5 < 5; ++k5) {
                a0l = __builtin_amdgcn_mfma_f32_16x16x32_bf16(axk[k5],     fa[k5],     a0l, 0, 0, 0);
                a0h = __builtin_amdgcn_mfma_f32_16x16x32_bf16(axk[k5 + 5], fa[k5 + 5], a0h, 0, 0, 0);
            }
            const f32x4 a0 = a0l + a0h;
            if (np < 9) {
#pragma unroll
                for (int ks = 0; ks < KS; ++ks)
                    fa[ks] = *(const short8*)(base + (size_t)((2 * np + 2) * KS + ks) * 1024);
            }
            f32x4 a1l = {0.f, 0.f, 0.f, 0.f}, a1h = {0.f, 0.f, 0.f, 0.f};
#pragma unroll
            for (int k5 = 0; k5 < 5; ++k5) {
                a1l = __builtin_amdgcn_mfma_f32_16x16x32_bf16(axk[k5],     fb[k5],     a1l, 0, 0, 0);
                a1h = __builtin_amdgcn_mfma_f32_16x16x32_bf16(axk[k5 + 5], fb[k5 + 5], a1h, 0, 0, 0);
            }
            const f32x4 a1 = a1l + a1h;
            const int c0 = 2 * np * 16 + lr;
            const int c1 = c0 + 16;
            if (mode == 0) {
#pragma unroll
                for (int r = 0; r < 4; ++r) {
                    const int row = g * 4 + r;
                    *(short*)(dst + swz(row, c0 * 2)) = (short)f2bf(a0[r]);
                    *(short*)(dst + swz(row, c1 * 2)) = (short)f2bf(a1[r]);
                }
            } else {
#pragma unroll
                for (int r = 0; r < 4; ++r) {
                    const int key = g * 4 + r;
                    *(short*)(dst + c0 * 32 + key * 2) = (short)f2bf(a0[r]);
                    *(short*)(dst + c1 * 32 + key * 2) = (short)f2bf(a1[r]);
                }
            }
        }
    };

    proj(0, kbuf, 0);    // Q -> kbuf
    proj(1, vbuf, 0);    // K -> vbuf

    // ---- scores via MFMA, all 8 heads: S^T = mfma(K, Q) ----
    // lane (g,lr): s[r] = S[query=lr][key=g*4+r]
    const float scale = 0.15811388300841897f;  // 40^-0.5
    const short8 z8 = {0, 0, 0, 0, 0, 0, 0, 0};
    uint2v ppk[8];   // packed p (4 bf16 = keys g*4..+3) per head
#pragma unroll
    for (int h = 0; h < 8; ++h) {
        const int cb = h * 80;   // byte base of head in a [16][640B] row
        short8 kf = *(const short8*)(vbuf + swz(lr, cb + g * 16));
        short8 qf = *(const short8*)(kbuf + swz(lr, cb + g * 16));
        short8 kt8 = *(const short8*)(vbuf + swz(lr, cb + 64)); // ch 32..39
        short8 qt8 = *(const short8*)(kbuf + swz(lr, cb + 64));
        short8 kt = (g == 0) ? kt8 : z8;   // zero-pad K=40 -> 32+8
        short8 qt = (g == 0) ? qt8 : z8;
        f32x4 c = {0.f, 0.f, 0.f, 0.f};
        c = __builtin_amdgcn_mfma_f32_16x16x32_bf16(kf, qf, c, 0, 0, 0);
        c = __builtin_amdgcn_mfma_f32_16x16x32_bf16(kt, qt, c, 0, 0, 0);
        float sv[4];
        float m4 = -1e30f;
#pragma unroll
        for (int r = 0; r < 4; ++r) {
            sv[r] = (g * 4 + r <= lr) ? c[r] * scale : -1e30f;  // causal
            m4 = fmaxf(m4, sv[r]);
        }
        m4 = fmaxf(m4, __shfl_xor(m4, 16));
        m4 = fmaxf(m4, __shfl_xor(m4, 32));
        float sum = 0.f;
#pragma unroll
        for (int r = 0; r < 4; ++r) { sv[r] = __expf(sv[r] - m4); sum += sv[r]; }
        sum += __shfl_xor(sum, 16);
        sum += __shfl_xor(sum, 32);
        const float inv = 1.f / sum;
        uint2v pk;
        pk[0] = (uint32_t)f2bf(sv[0] * inv) | ((uint32_t)f2bf(sv[1] * inv) << 16);
        pk[1] = (uint32_t)f2bf(sv[2] * inv) | ((uint32_t)f2bf(sv[3] * inv) << 16);
        ppk[h] = pk;
    }

    proj(2, kbuf, 1);    // V' (transposed [320 cols][16 keys x 2B]) over Q

    // ---- PV via MFMA; attn-out -> vbuf (K dead) ----
#pragma unroll
    for (int h = 0; h < 8; ++h) {
        // build A-frag: P[query=lr][keys g*8..+7], keys 16..31 zero (K=32 pad)
        uint2v own = ppk[h];
        uint2v x16;
        x16[0] = (uint32_t)__shfl_xor((int)own[0], 16);
        x16[1] = (uint32_t)__shfl_xor((int)own[1], 16);
        uint4v pair;
        pair[0] = ((g & 1) == 0) ? own[0] : x16[0];   // keys (g>>1)*8 .. +3
        pair[1] = ((g & 1) == 0) ? own[1] : x16[1];
        pair[2] = ((g & 1) == 0) ? x16[0] : own[0];   // keys (g>>1)*8+4 .. +7
        pair[3] = ((g & 1) == 0) ? x16[1] : own[1];
        uint4v rec;
#pragma unroll
        for (int i = 0; i < 4; ++i) rec[i] = (uint32_t)__shfl_xor((int)pair[i], 32);
        uint4v af4;
#pragma unroll
        for (int i = 0; i < 4; ++i)
            af4[i] = (g == 0) ? pair[i] : (g == 1) ? rec[i] : 0u;
        const short8 af = *(const short8*)&af4;

#pragma unroll
        for (int t = 0; t < 3; ++t) {
            // d-col tiles 16,16,8: t=2 clamps lr (duplicate cols, not written)
            const int lcol = (t == 2) ? (lr & 7) : lr;
            const int col  = h * 40 + t * 16 + lcol;
            const short8 bf = *(const short8*)(kbuf + col * 32 + g * 16); // V'
            f32x4 o = {0.f, 0.f, 0.f, 0.f};
            o = __builtin_amdgcn_mfma_f32_16x16x32_bf16(af, bf, o, 0, 0, 0);
            if (t < 2 || lr < 8) {
#pragma unroll
                for (int r = 0; r < 4; ++r)
                    *(short*)(vbuf + swz(g * 4 + r, col * 2)) = (short)f2bf(o[r]);
            }
        }
    }

    // ---- output projection: out = ao @ Wo.T + bo ----
    short8 aof[KS];
#pragma unroll
    for (int ks = 0; ks < KS; ++ks)
        aof[ks] = *(const short8*)(vbuf + swz(lr, ks * 64 + g * 16));

    {
        const char* base = wpk + lane * 16 + (size_t)(3 * NT) * KS * 1024;
        short8 fa[KS], fb[KS];
#pragma unroll
        for (int ks = 0; ks < KS; ++ks)
            fa[ks] = *(const short8*)(base + (size_t)ks * 1024);
#pragma unroll 1
        for (int np = 0; np < 10; ++np) {
#pragma unroll
            for (int ks = 0; ks < KS; ++ks)
                fb[ks] = *(const short8*)(base + (size_t)((2 * np + 1) * KS + ks) * 1024);
            f32x4 a0l = {0.f, 0.f, 0.f, 0.f}, a0h = {0.f, 0.f, 0.f, 0.f};
#pragma unroll
            for (int k5 = 0; k5 < 5; ++k5) {
                a0l = __builtin_amdgcn_mfma_f32_16x16x32_bf16(aof[k5],     fa[k5],     a0l, 0, 0, 0);
                a0h = __builtin_amdgcn_mfma_f32_16x16x32_bf16(aof[k5 + 5], fa[k5 + 5], a0h, 0, 0, 0);
            }
            const f32x4 a0 = a0l + a0h;
            if (np < 9) {
#pragma unroll
                for (int ks = 0; ks < KS; ++ks)
                    fa[ks] = *(const short8*)(base + (size_t)((2 * np + 2) * KS + ks) * 1024);
            }
            f32x4 a1l = {0.f, 0.f, 0.f, 0.f}, a1h = {0.f, 0.f, 0.f, 0.f};
#pragma unroll
            for (int k5 = 0; k5 < 5; ++k5) {
                a1l = __builtin_amdgcn_mfma_f32_16x16x32_bf16(aof[k5],     fb[k5],     a1l, 0, 0, 0);
                a1h = __builtin_amdgcn_mfma_f32_16x16x32_bf16(aof[k5 + 5], fb[k5 + 5], a1h, 0, 0, 0);
            }
            const f32x4 a1 = a1l + a1h;

            const int c0 = 2 * np * 16 + lr;
            const int c1 = c0 + 16;
            const float bias0 = bo[c0];
            const float bias1 = bo[c1];
            // paired stores cover one full 128B line per output row
#pragma unroll
            for (int r = 0; r < 4; ++r) {
                float* rowp = out + ((size_t)(bi * F + g * 4 + r) * DDIM + di) * CDIM;
                rowp[c0] = a0[r] + bias0;
                rowp[c1] = a1[r] + bias1;
            }
        }
    }
}

extern "C" void kernel_launch(void* const* d_in, const int* in_sizes, int n_in,
                              void* d_out, int out_size, void* d_ws, size_t ws_size,
                              hipStream_t stream) {
    const float* hs = (const float*)d_in[0];
    const float* Wq = (const float*)d_in[1];
    const float* Wk = (const float*)d_in[2];
    const float* Wv = (const float*)d_in[3];
    const float* Wo = (const float*)d_in[4];
    const float* bo = (const float*)d_in[5];
    float* out = (float*)d_out;
    char* wpk = (char*)d_ws;   // 4*200*1024 = 819200 B of packed bf16 weights

    pack_weights_kernel<<<dim3((4 * NT * KS * 64 + 255) / 256), dim3(256), 0, stream>>>(
        Wq, Wk, Wv, Wo, wpk);

    const int lds = WPB * 20480;   // 81920 B -> 2 blocks/CU (8 waves/CU)
    (void)hipFuncSetAttribute((const void*)temporal_attn_kernel,
                              hipFuncAttributeMaxDynamicSharedMemorySize, lds);
    temporal_attn_kernel<<<dim3(NSEQ / WPB), dim3(THREADS), lds, stream>>>(
        hs, wpk, bo, out);
}

// Round 14
// 238.525 us; speedup vs baseline: 1.2516x; 1.0587x over previous
//
#include <hip/hip_runtime.h>
#include <stdint.h>

#define F 16
#define CDIM 320
#define DDIM 4096
#define NSEQ 8192
#define THREADS 128   // 2 waves/block; each wave owns 2 sequences
#define NT 20
#define KS 10

typedef __attribute__((ext_vector_type(8))) short short8;
typedef __attribute__((ext_vector_type(4))) float f32x4;
typedef __attribute__((ext_vector_type(2))) unsigned int uint2v;
typedef __attribute__((ext_vector_type(4))) unsigned int uint4v;

__device__ __forceinline__ unsigned short f2bf(float f) {
    union { float f; uint32_t u; } v; v.f = f;
    uint32_t r = v.u + 0x7FFFu + ((v.u >> 16) & 1u);   // RTNE
    return (unsigned short)(r >> 16);
}
// [16][320] bf16 tile swizzle, row stride 640 B, 16B chunks, chunk^(row&7)
// bijective per row and in-bounds (40 chunks = 5 groups of 8).
__device__ __forceinline__ int swz(int row, int b) {
    return row * 640 + (b ^ ((row & 7) << 4));
}

// One-time: pack Wq/Wk/Wv/Wo (fp32 row-major [320][320]) into bf16 B-fragment
// order. Fragment (m, nt, ks) is a 1KB block: lane (g,lr) holds
// W[nt*16+lr][ks*32+g*8 .. +7]. Byte offset = ((m*NT+nt)*KS+ks)*1024 + lane*16.
__global__ __launch_bounds__(256)
void pack_weights_kernel(const float* __restrict__ Wq, const float* __restrict__ Wk,
                         const float* __restrict__ Wv, const float* __restrict__ Wo,
                         char* __restrict__ pk)
{
    const int t = blockIdx.x * 256 + threadIdx.x;
    if (t >= 4 * NT * KS * 64) return;
    const int lane = t & 63;
    const int rest = t >> 6;
    const int ks = rest % KS;
    const int nt = (rest / KS) % NT;
    const int m  = rest / (KS * NT);
    const float* W = (m == 0) ? Wq : (m == 1) ? Wk : (m == 2) ? Wv : Wo;
    const int g = lane >> 4, lr = lane & 15;
    const float* src = W + (size_t)(nt * 16 + lr) * CDIM + ks * 32 + g * 8;
    const f32x4 a = *(const f32x4*)src;
    const f32x4 b = *(const f32x4*)(src + 4);
    float vals[8] = {a[0], a[1], a[2], a[3], b[0], b[1], b[2], b[3]};
    short8 o;
#pragma unroll
    for (int j = 0; j < 8; ++j) o[j] = (short)f2bf(vals[j]);
    *(short8*)(pk + (size_t)t * 16) = o;
}

// R13 structure with 2 SEQUENCES PER WAVE: each weight fragment read feeds
// 2 MFMAs -> weight-stream bytes/CU halve (the measured bottleneck: 6.5 GB
// of L2/TCP traffic was ~all of R13's wall). LDS 80 KB/block -> 2 blocks/CU
// -> 1 wave/SIMD (deliberate: byte-bound phases scale with bytes not waves).
// launch_bounds(128,1) -> 512-VGPR cap: the ~200-reg live set CANNOT spill.
// All per-seq state hand-duplicated _A/_B (no runtime seq indexing).
__global__ __launch_bounds__(THREADS, 1)
void temporal_attn_kernel(const float* __restrict__ hs,
                          const char* __restrict__ wpk,
                          const float* __restrict__ bo,
                          float* __restrict__ out)
{
    extern __shared__ __align__(16) char smem[];
    const int tid  = threadIdx.x;
    const int lane = tid & 63;
    const int wave = tid >> 6;
    const int g    = lane >> 4;
    const int lr   = lane & 15;

    const int seqA = blockIdx.x * 4 + wave * 2;   // seqB = seqA + 1, same bi
    const int bi  = seqA >> 12;
    const int di  = seqA & (DDIM - 1);

    char* const kbufA = smem + wave * 40960;   // seq A: Q, then V'
    char* const vbufA = kbufA + 10240;         // seq A: K, then attn-out
    char* const kbufB = kbufA + 20480;         // seq B: Q, then V'
    char* const vbufB = kbufA + 30720;         // seq B: K, then attn-out

    // ---- load x rows for BOTH seqs, add PE (trig computed once), pack bf16 ----
    const float* xrowA = hs + ((size_t)(bi * F + lr) * DDIM + di) * CDIM;
    const float* xrowB = xrowA + CDIM;         // seqB = seqA+1 -> +320 floats
    short8 axkA[KS], axkB[KS];
#pragma unroll
    for (int ks = 0; ks < KS; ++ks) {
        const int k0 = ks * 32 + g * 8;
        const f32x4 aA = __builtin_nontemporal_load((const f32x4*)(xrowA + k0));
        const f32x4 bA = __builtin_nontemporal_load((const f32x4*)(xrowA + k0 + 4));
        const f32x4 aB = __builtin_nontemporal_load((const f32x4*)(xrowB + k0));
        const f32x4 bB = __builtin_nontemporal_load((const f32x4*)(xrowB + k0 + 4));
        float xvA[8] = {aA[0], aA[1], aA[2], aA[3], bA[0], bA[1], bA[2], bA[3]};
        float xvB[8] = {aB[0], aB[1], aB[2], aB[3], bB[0], bB[1], bB[2], bB[3]};
#pragma unroll
        for (int jj = 0; jj < 4; ++jj) {
            const float c0 = (float)(k0 + 2 * jj);
            const float dv = __expf(c0 * -0.028782313662425575f); // -ln(1e4)/320
            const float ang = (float)lr * dv;                      // pos = frame
            const float sn = __sinf(ang), cs = __cosf(ang);        // PE: seq-indep
            xvA[2 * jj] += sn;  xvA[2 * jj + 1] += cs;
            xvB[2 * jj] += sn;  xvB[2 * jj + 1] += cs;
        }
        short8 tA, tB;
#pragma unroll
        for (int j = 0; j < 8; ++j) { tA[j] = (short)f2bf(xvA[j]); tB[j] = (short)f2bf(xvB[j]); }
        axkA[ks] = tA;  axkB[ks] = tB;
    }

    // ---- projection pass: shared fragments feed BOTH seqs' MFMAs ----
    // mode 0: standard swizzled [16][640B]; mode 1: transposed V' [320][32B]
    auto proj = [&](int m, char* dA, char* dB, int mode) {
        const char* base = wpk + lane * 16 + (size_t)(m * NT) * KS * 1024;
        short8 fa[KS], fb[KS];
#pragma unroll
        for (int ks = 0; ks < KS; ++ks)
            fa[ks] = *(const short8*)(base + (size_t)ks * 1024);
#pragma unroll 1
        for (int np = 0; np < 10; ++np) {
#pragma unroll
            for (int ks = 0; ks < KS; ++ks)
                fb[ks] = *(const short8*)(base + (size_t)((2 * np + 1) * KS + ks) * 1024);
            f32x4 a0A = {0.f, 0.f, 0.f, 0.f}, a0B = {0.f, 0.f, 0.f, 0.f};
#pragma unroll
            for (int ks = 0; ks < KS; ++ks) {
                a0A = __builtin_amdgcn_mfma_f32_16x16x32_bf16(axkA[ks], fa[ks], a0A, 0, 0, 0);
                a0B = __builtin_amdgcn_mfma_f32_16x16x32_bf16(axkB[ks], fa[ks], a0B, 0, 0, 0);
            }
            if (np < 9) {
#pragma unroll
                for (int ks = 0; ks < KS; ++ks)
                    fa[ks] = *(const short8*)(base + (size_t)((2 * np + 2) * KS + ks) * 1024);
            }
            f32x4 a1A = {0.f, 0.f, 0.f, 0.f}, a1B = {0.f, 0.f, 0.f, 0.f};
#pragma unroll
            for (int ks = 0; ks < KS; ++ks) {
                a1A = __builtin_amdgcn_mfma_f32_16x16x32_bf16(axkA[ks], fb[ks], a1A, 0, 0, 0);
                a1B = __builtin_amdgcn_mfma_f32_16x16x32_bf16(axkB[ks], fb[ks], a1B, 0, 0, 0);
            }
            const int c0 = 2 * np * 16 + lr;
            const int c1 = c0 + 16;
            if (mode == 0) {
#pragma unroll
                for (int r = 0; r < 4; ++r) {
                    const int row = g * 4 + r;
                    *(short*)(dA + swz(row, c0 * 2)) = (short)f2bf(a0A[r]);
                    *(short*)(dA + swz(row, c1 * 2)) = (short)f2bf(a1A[r]);
                    *(short*)(dB + swz(row, c0 * 2)) = (short)f2bf(a0B[r]);
                    *(short*)(dB + swz(row, c1 * 2)) = (short)f2bf(a1B[r]);
                }
            } else {
#pragma unroll
                for (int r = 0; r < 4; ++r) {
                    const int key = g * 4 + r;
                    *(short*)(dA + c0 * 32 + key * 2) = (short)f2bf(a0A[r]);
                    *(short*)(dA + c1 * 32 + key * 2) = (short)f2bf(a1A[r]);
                    *(short*)(dB + c0 * 32 + key * 2) = (short)f2bf(a0B[r]);
                    *(short*)(dB + c1 * 32 + key * 2) = (short)f2bf(a1B[r]);
                }
            }
        }
    };

    proj(0, kbufA, kbufB, 0);   // Q
    proj(1, vbufA, vbufB, 0);   // K

    // ---- scores via MFMA (S^T = mfma(K, Q)), per seq ----
    const float scale = 0.15811388300841897f;  // 40^-0.5
    const short8 z8 = {0, 0, 0, 0, 0, 0, 0, 0};
    uint2v ppkA[8], ppkB[8];
#pragma unroll
    for (int h = 0; h < 8; ++h) {
        const int cb = h * 80;
        short8 kf = *(const short8*)(vbufA + swz(lr, cb + g * 16));
        short8 qf = *(const short8*)(kbufA + swz(lr, cb + g * 16));
        short8 kt8 = *(const short8*)(vbufA + swz(lr, cb + 64));
        short8 qt8 = *(const short8*)(kbufA + swz(lr, cb + 64));
        short8 kt = (g == 0) ? kt8 : z8;
        short8 qt = (g == 0) ? qt8 : z8;
        f32x4 c = {0.f, 0.f, 0.f, 0.f};
        c = __builtin_amdgcn_mfma_f32_16x16x32_bf16(kf, qf, c, 0, 0, 0);
        c = __builtin_amdgcn_mfma_f32_16x16x32_bf16(kt, qt, c, 0, 0, 0);
        float sv[4]; float m4 = -1e30f;
#pragma unroll
        for (int r = 0; r < 4; ++r) {
            sv[r] = (g * 4 + r <= lr) ? c[r] * scale : -1e30f;
            m4 = fmaxf(m4, sv[r]);
        }
        m4 = fmaxf(m4, __shfl_xor(m4, 16));
        m4 = fmaxf(m4, __shfl_xor(m4, 32));
        float sum = 0.f;
#pragma unroll
        for (int r = 0; r < 4; ++r) { sv[r] = __expf(sv[r] - m4); sum += sv[r]; }
        sum += __shfl_xor(sum, 16);
        sum += __shfl_xor(sum, 32);
        const float inv = 1.f / sum;
        uint2v pk;
        pk[0] = (uint32_t)f2bf(sv[0] * inv) | ((uint32_t)f2bf(sv[1] * inv) << 16);
        pk[1] = (uint32_t)f2bf(sv[2] * inv) | ((uint32_t)f2bf(sv[3] * inv) << 16);
        ppkA[h] = pk;
    }
#pragma unroll
    for (int h = 0; h < 8; ++h) {
        const int cb = h * 80;
        short8 kf = *(const short8*)(vbufB + swz(lr, cb + g * 16));
        short8 qf = *(const short8*)(kbufB + swz(lr, cb + g * 16));
        short8 kt8 = *(const short8*)(vbufB + swz(lr, cb + 64));
        short8 qt8 = *(const short8*)(kbufB + swz(lr, cb + 64));
        short8 kt = (g == 0) ? kt8 : z8;
        short8 qt = (g == 0) ? qt8 : z8;
        f32x4 c = {0.f, 0.f, 0.f, 0.f};
        c = __builtin_amdgcn_mfma_f32_16x16x32_bf16(kf, qf, c, 0, 0, 0);
        c = __builtin_amdgcn_mfma_f32_16x16x32_bf16(kt, qt, c, 0, 0, 0);
        float sv[4]; float m4 = -1e30f;
#pragma unroll
        for (int r = 0; r < 4; ++r) {
            sv[r] = (g * 4 + r <= lr) ? c[r] * scale : -1e30f;
            m4 = fmaxf(m4, sv[r]);
        }
        m4 = fmaxf(m4, __shfl_xor(m4, 16));
        m4 = fmaxf(m4, __shfl_xor(m4, 32));
        float sum = 0.f;
#pragma unroll
        for (int r = 0; r < 4; ++r) { sv[r] = __expf(sv[r] - m4); sum += sv[r]; }
        sum += __shfl_xor(sum, 16);
        sum += __shfl_xor(sum, 32);
        const float inv = 1.f / sum;
        uint2v pk;
        pk[0] = (uint32_t)f2bf(sv[0] * inv) | ((uint32_t)f2bf(sv[1] * inv) << 16);
        pk[1] = (uint32_t)f2bf(sv[2] * inv) | ((uint32_t)f2bf(sv[3] * inv) << 16);
        ppkB[h] = pk;
    }

    proj(2, kbufA, kbufB, 1);   // V' (transposed) over Q

    // ---- PV via MFMA; attn-out -> vbuf (K dead), per seq ----
#pragma unroll
    for (int h = 0; h < 8; ++h) {
        uint2v own = ppkA[h];
        uint2v x16;
        x16[0] = (uint32_t)__shfl_xor((int)own[0], 16);
        x16[1] = (uint32_t)__shfl_xor((int)own[1], 16);
        uint4v pair;
        pair[0] = ((g & 1) == 0) ? own[0] : x16[0];
        pair[1] = ((g & 1) == 0) ? own[1] : x16[1];
        pair[2] = ((g & 1) == 0) ? x16[0] : own[0];
        pair[3] = ((g & 1) == 0) ? x16[1] : own[1];
        uint4v rec;
#pragma unroll
        for (int i = 0; i < 4; ++i) rec[i] = (uint32_t)__shfl_xor((int)pair[i], 32);
        uint4v af4;
#pragma unroll
        for (int i = 0; i < 4; ++i)
            af4[i] = (g == 0) ? pair[i] : (g == 1) ? rec[i] : 0u;
        const short8 af = *(const short8*)&af4;
#pragma unroll
        for (int t = 0; t < 3; ++t) {
            const int lcol = (t == 2) ? (lr & 7) : lr;
            const int col  = h * 40 + t * 16 + lcol;
            const short8 bf = *(const short8*)(kbufA + col * 32 + g * 16);
            f32x4 o = {0.f, 0.f, 0.f, 0.f};
            o = __builtin_amdgcn_mfma_f32_16x16x32_bf16(af, bf, o, 0, 0, 0);
            if (t < 2 || lr < 8) {
#pragma unroll
                for (int r = 0; r < 4; ++r)
                    *(short*)(vbufA + swz(g * 4 + r, col * 2)) = (short)f2bf(o[r]);
            }
        }
    }
#pragma unroll
    for (int h = 0; h < 8; ++h) {
        uint2v own = ppkB[h];
        uint2v x16;
        x16[0] = (uint32_t)__shfl_xor((int)own[0], 16);
        x16[1] = (uint32_t)__shfl_xor((int)own[1], 16);
        uint4v pair;
        pair[0] = ((g & 1) == 0) ? own[0] : x16[0];
        pair[1] = ((g & 1) == 0) ? own[1] : x16[1];
        pair[2] = ((g & 1) == 0) ? x16[0] : own[0];
        pair[3] = ((g & 1) == 0) ? x16[1] : own[1];
        uint4v rec;
#pragma unroll
        for (int i = 0; i < 4; ++i) rec[i] = (uint32_t)__shfl_xor((int)pair[i], 32);
        uint4v af4;
#pragma unroll
        for (int i = 0; i < 4; ++i)
            af4[i] = (g == 0) ? pair[i] : (g == 1) ? rec[i] : 0u;
        const short8 af = *(const short8*)&af4;
#pragma unroll
        for (int t = 0; t < 3; ++t) {
            const int lcol = (t == 2) ? (lr & 7) : lr;
            const int col  = h * 40 + t * 16 + lcol;
            const short8 bf = *(const short8*)(kbufB + col * 32 + g * 16);
            f32x4 o = {0.f, 0.f, 0.f, 0.f};
            o = __builtin_amdgcn_mfma_f32_16x16x32_bf16(af, bf, o, 0, 0, 0);
            if (t < 2 || lr < 8) {
#pragma unroll
                for (int r = 0; r < 4; ++r)
                    *(short*)(vbufB + swz(g * 4 + r, col * 2)) = (short)f2bf(o[r]);
            }
        }
    }

    // ---- output projection: shared Wo fragments feed both seqs ----
    short8 aofA[KS], aofB[KS];
#pragma unroll
    for (int ks = 0; ks < KS; ++ks) {
        aofA[ks] = *(const short8*)(vbufA + swz(lr, ks * 64 + g * 16));
        aofB[ks] = *(const short8*)(vbufB + swz(lr, ks * 64 + g * 16));
    }
    {
        const char* base = wpk + lane * 16 + (size_t)(3 * NT) * KS * 1024;
        short8 fa[KS], fb[KS];
#pragma unroll
        for (int ks = 0; ks < KS; ++ks)
            fa[ks] = *(const short8*)(base + (size_t)ks * 1024);
#pragma unroll 1
        for (int np = 0; np < 10; ++np) {
#pragma unroll
            for (int ks = 0; ks < KS; ++ks)
                fb[ks] = *(const short8*)(base + (size_t)((2 * np + 1) * KS + ks) * 1024);
            f32x4 a0A = {0.f, 0.f, 0.f, 0.f}, a0B = {0.f, 0.f, 0.f, 0.f};
#pragma unroll
            for (int ks = 0; ks < KS; ++ks) {
                a0A = __builtin_amdgcn_mfma_f32_16x16x32_bf16(aofA[ks], fa[ks], a0A, 0, 0, 0);
                a0B = __builtin_amdgcn_mfma_f32_16x16x32_bf16(aofB[ks], fa[ks], a0B, 0, 0, 0);
            }
            if (np < 9) {
#pragma unroll
                for (int ks = 0; ks < KS; ++ks)
                    fa[ks] = *(const short8*)(base + (size_t)((2 * np + 2) * KS + ks) * 1024);
            }
            f32x4 a1A = {0.f, 0.f, 0.f, 0.f}, a1B = {0.f, 0.f, 0.f, 0.f};
#pragma unroll
            for (int ks = 0; ks < KS; ++ks) {
                a1A = __builtin_amdgcn_mfma_f32_16x16x32_bf16(aofA[ks], fb[ks], a1A, 0, 0, 0);
                a1B = __builtin_amdgcn_mfma_f32_16x16x32_bf16(aofB[ks], fb[ks], a1B, 0, 0, 0);
            }
            const int c0 = 2 * np * 16 + lr;
            const int c1 = c0 + 16;
            const float bias0 = bo[c0];
            const float bias1 = bo[c1];
            // paired stores: one full 128B line per output row per seq
#pragma unroll
            for (int r = 0; r < 4; ++r) {
                float* rowpA = out + ((size_t)(bi * F + g * 4 + r) * DDIM + di) * CDIM;
                float* rowpB = rowpA + CDIM;
                rowpA[c0] = a0A[r] + bias0;
                rowpA[c1] = a1A[r] + bias1;
                rowpB[c0] = a0B[r] + bias0;
                rowpB[c1] = a1B[r] + bias1;
            }
        }
    }
}

extern "C" void kernel_launch(void* const* d_in, const int* in_sizes, int n_in,
                              void* d_out, int out_size, void* d_ws, size_t ws_size,
                              hipStream_t stream) {
    const float* hs = (const float*)d_in[0];
    const float* Wq = (const float*)d_in[1];
    const float* Wk = (const float*)d_in[2];
    const float* Wv = (const float*)d_in[3];
    const float* Wo = (const float*)d_in[4];
    const float* bo = (const float*)d_in[5];
    float* out = (float*)d_out;
    char* wpk = (char*)d_ws;   // 4*200*1024 = 819200 B of packed bf16 weights

    pack_weights_kernel<<<dim3((4 * NT * KS * 64 + 255) / 256), dim3(256), 0, stream>>>(
        Wq, Wk, Wv, Wo, wpk);

    const int lds = 2 * 40960;   // 81920 B -> 2 blocks/CU (4 waves/CU)
    (void)hipFuncSetAttribute((const void*)temporal_attn_kernel,
                              hipFuncAttributeMaxDynamicSharedMemorySize, lds);
    temporal_attn_kernel<<<dim3(NSEQ / 4), dim3(THREADS), lds, stream>>>(
        hs, wpk, bo, out);
}

// Round 16
// 222.084 us; speedup vs baseline: 1.3442x; 1.0740x over previous
//
#include <hip/hip_runtime.h>
#include <stdint.h>

#define F 16
#define CDIM 320
#define DDIM 4096
#define NSEQ 8192
#define THREADS 128   // 2 waves/block; each wave owns 2 sequences
#define NT 20
#define KS 10

typedef __attribute__((ext_vector_type(8))) short short8;
typedef __attribute__((ext_vector_type(4))) float f32x4;
typedef __attribute__((ext_vector_type(2))) unsigned int uint2v;
typedef __attribute__((ext_vector_type(4))) unsigned int uint4v;

__device__ __forceinline__ unsigned short f2bf(float f) {
    union { float f; uint32_t u; } v; v.f = f;
    uint32_t r = v.u + 0x7FFFu + ((v.u >> 16) & 1u);   // RTNE
    return (unsigned short)(r >> 16);
}
// [16][320] bf16 tile swizzle, row stride 640 B, 16B chunks, chunk^(row&7)
// bijective per row and in-bounds (40 chunks = 5 groups of 8).
__device__ __forceinline__ int swz(int row, int b) {
    return row * 640 + (b ^ ((row & 7) << 4));
}

// One-time: pack Wq/Wk/Wv/Wo (fp32 row-major [320][320]) into bf16 B-fragment
// order. Fragment (m, nt, ks) is a 1KB block: lane (g,lr) holds
// W[nt*16+lr][ks*32+g*8 .. +7]. Byte offset = ((m*NT+nt)*KS+ks)*1024 + lane*16.
__global__ __launch_bounds__(256)
void pack_weights_kernel(const float* __restrict__ Wq, const float* __restrict__ Wk,
                         const float* __restrict__ Wv, const float* __restrict__ Wo,
                         char* __restrict__ pk)
{
    const int t = blockIdx.x * 256 + threadIdx.x;
    if (t >= 4 * NT * KS * 64) return;
    const int lane = t & 63;
    const int rest = t >> 6;
    const int ks = rest % KS;
    const int nt = (rest / KS) % NT;
    const int m  = rest / (KS * NT);
    const float* W = (m == 0) ? Wq : (m == 1) ? Wk : (m == 2) ? Wv : Wo;
    const int g = lane >> 4, lr = lane & 15;
    const float* src = W + (size_t)(nt * 16 + lr) * CDIM + ks * 32 + g * 8;
    const f32x4 a = *(const f32x4*)src;
    const f32x4 b = *(const f32x4*)(src + 4);
    float vals[8] = {a[0], a[1], a[2], a[3], b[0], b[1], b[2], b[3]};
    short8 o;
#pragma unroll
    for (int j = 0; j < 8; ++j) o[j] = (short)f2bf(vals[j]);
    *(short8*)(pk + (size_t)t * 16) = o;
}

// R14 shell (clean, 512-VGPR cap: spill-impossible) + latency-exposure fixes:
//  - prefetch distance 2 in all weight passes (4 fragment arrays): each
//    10-load batch covered by ~40 MFMAs + stores before first use.
//  - seq A/B attention merged per head (independent chains interleave).
//  - R15's vswz REVERTED: it XOR'd bit4 into 32B record bases -> records
//    overlapped (cols 7/9 collided) -> absmax 2.46. Plain [320][32B] V'
//    restored (bank conflicts measured negligible: ~10k cyc/CU vs 740k wall).
__global__ __launch_bounds__(THREADS, 1)
void temporal_attn_kernel(const float* __restrict__ hs,
                          const char* __restrict__ wpk,
                          const float* __restrict__ bo,
                          float* __restrict__ out)
{
    extern __shared__ __align__(16) char smem[];
    const int tid  = threadIdx.x;
    const int lane = tid & 63;
    const int wave = tid >> 6;
    const int g    = lane >> 4;
    const int lr   = lane & 15;

    const int seqA = blockIdx.x * 4 + wave * 2;   // seqB = seqA + 1, same bi
    const int bi  = seqA >> 12;
    const int di  = seqA & (DDIM - 1);

    char* const kbufA = smem + wave * 40960;   // seq A: Q, then V'
    char* const vbufA = kbufA + 10240;         // seq A: K, then attn-out
    char* const kbufB = kbufA + 20480;         // seq B: Q, then V'
    char* const vbufB = kbufA + 30720;         // seq B: K, then attn-out

    // ---- load x rows for BOTH seqs, add PE (trig computed once), pack bf16 ----
    const float* xrowA = hs + ((size_t)(bi * F + lr) * DDIM + di) * CDIM;
    const float* xrowB = xrowA + CDIM;         // seqB = seqA+1 -> +320 floats
    short8 axkA[KS], axkB[KS];
#pragma unroll
    for (int ks = 0; ks < KS; ++ks) {
        const int k0 = ks * 32 + g * 8;
        const f32x4 aA = __builtin_nontemporal_load((const f32x4*)(xrowA + k0));
        const f32x4 bA = __builtin_nontemporal_load((const f32x4*)(xrowA + k0 + 4));
        const f32x4 aB = __builtin_nontemporal_load((const f32x4*)(xrowB + k0));
        const f32x4 bB = __builtin_nontemporal_load((const f32x4*)(xrowB + k0 + 4));
        float xvA[8] = {aA[0], aA[1], aA[2], aA[3], bA[0], bA[1], bA[2], bA[3]};
        float xvB[8] = {aB[0], aB[1], aB[2], aB[3], bB[0], bB[1], bB[2], bB[3]};
#pragma unroll
        for (int jj = 0; jj < 4; ++jj) {
            const float c0 = (float)(k0 + 2 * jj);
            const float dv = __expf(c0 * -0.028782313662425575f); // -ln(1e4)/320
            const float ang = (float)lr * dv;                      // pos = frame
            const float sn = __sinf(ang), cs = __cosf(ang);        // PE: seq-indep
            xvA[2 * jj] += sn;  xvA[2 * jj + 1] += cs;
            xvB[2 * jj] += sn;  xvB[2 * jj + 1] += cs;
        }
        short8 tA, tB;
#pragma unroll
        for (int j = 0; j < 8; ++j) { tA[j] = (short)f2bf(xvA[j]); tB[j] = (short)f2bf(xvB[j]); }
        axkA[ks] = tA;  axkB[ks] = tB;
    }

    // ---- projection: shared fragments feed both seqs; prefetch distance 2 ----
    // mode 0: standard swizzled [16][640B]; mode 1: V' [320 cols][32B records]
    auto proj = [&](int m, char* dA, char* dB, int mode) {
        const char* base = wpk + lane * 16 + (size_t)(m * NT) * KS * 1024;
        short8 f0[KS], f1[KS], f2[KS], f3[KS];
#pragma unroll
        for (int ks = 0; ks < KS; ++ks) {
            f0[ks] = *(const short8*)(base + (size_t)ks * 1024);
            f1[ks] = *(const short8*)(base + (size_t)(KS + ks) * 1024);
        }
        auto store2 = [&](int ti, const f32x4& aA, const f32x4& aB) {
            const int c = ti * 16 + lr;
            if (mode == 0) {
#pragma unroll
                for (int r = 0; r < 4; ++r) {
                    const int row = g * 4 + r;
                    *(short*)(dA + swz(row, c * 2)) = (short)f2bf(aA[r]);
                    *(short*)(dB + swz(row, c * 2)) = (short)f2bf(aB[r]);
                }
            } else {
#pragma unroll
                for (int r = 0; r < 4; ++r) {
                    const int key = g * 4 + r;
                    *(short*)(dA + c * 32 + key * 2) = (short)f2bf(aA[r]);
                    *(short*)(dB + c * 32 + key * 2) = (short)f2bf(aB[r]);
                }
            }
        };
#pragma unroll 1
        for (int np2 = 0; np2 < 5; ++np2) {
            const int t = np2 * 4;
            // prefetch tiles t+2, t+3 (consumed after ~40 MFMAs + stores)
#pragma unroll
            for (int ks = 0; ks < KS; ++ks) {
                f2[ks] = *(const short8*)(base + (size_t)((t + 2) * KS + ks) * 1024);
                f3[ks] = *(const short8*)(base + (size_t)((t + 3) * KS + ks) * 1024);
            }
            {
                f32x4 a0A = {0,0,0,0}, a0B = {0,0,0,0}, a1A = {0,0,0,0}, a1B = {0,0,0,0};
#pragma unroll
                for (int ks = 0; ks < KS; ++ks) {
                    a0A = __builtin_amdgcn_mfma_f32_16x16x32_bf16(axkA[ks], f0[ks], a0A, 0, 0, 0);
                    a0B = __builtin_amdgcn_mfma_f32_16x16x32_bf16(axkB[ks], f0[ks], a0B, 0, 0, 0);
                    a1A = __builtin_amdgcn_mfma_f32_16x16x32_bf16(axkA[ks], f1[ks], a1A, 0, 0, 0);
                    a1B = __builtin_amdgcn_mfma_f32_16x16x32_bf16(axkB[ks], f1[ks], a1B, 0, 0, 0);
                }
                store2(t,     a0A, a0B);
                store2(t + 1, a1A, a1B);
            }
            if (np2 < 4) {   // prefetch tiles t+4, t+5
#pragma unroll
                for (int ks = 0; ks < KS; ++ks) {
                    f0[ks] = *(const short8*)(base + (size_t)((t + 4) * KS + ks) * 1024);
                    f1[ks] = *(const short8*)(base + (size_t)((t + 5) * KS + ks) * 1024);
                }
            }
            {
                f32x4 a2A = {0,0,0,0}, a2B = {0,0,0,0}, a3A = {0,0,0,0}, a3B = {0,0,0,0};
#pragma unroll
                for (int ks = 0; ks < KS; ++ks) {
                    a2A = __builtin_amdgcn_mfma_f32_16x16x32_bf16(axkA[ks], f2[ks], a2A, 0, 0, 0);
                    a2B = __builtin_amdgcn_mfma_f32_16x16x32_bf16(axkB[ks], f2[ks], a2B, 0, 0, 0);
                    a3A = __builtin_amdgcn_mfma_f32_16x16x32_bf16(axkA[ks], f3[ks], a3A, 0, 0, 0);
                    a3B = __builtin_amdgcn_mfma_f32_16x16x32_bf16(axkB[ks], f3[ks], a3B, 0, 0, 0);
                }
                store2(t + 2, a2A, a2B);
                store2(t + 3, a3A, a3B);
            }
        }
    };

    proj(0, kbufA, kbufB, 0);   // Q
    proj(1, vbufA, vbufB, 0);   // K

    // ---- scores via MFMA (S^T = mfma(K, Q)), seqs A and B interleaved ----
    const float scale = 0.15811388300841897f;  // 40^-0.5
    const short8 z8 = {0, 0, 0, 0, 0, 0, 0, 0};
    uint2v ppkA[8], ppkB[8];
#pragma unroll
    for (int h = 0; h < 8; ++h) {
        const int cb = h * 80;
        short8 kfA = *(const short8*)(vbufA + swz(lr, cb + g * 16));
        short8 qfA = *(const short8*)(kbufA + swz(lr, cb + g * 16));
        short8 kfB = *(const short8*)(vbufB + swz(lr, cb + g * 16));
        short8 qfB = *(const short8*)(kbufB + swz(lr, cb + g * 16));
        short8 ktA8 = *(const short8*)(vbufA + swz(lr, cb + 64));
        short8 qtA8 = *(const short8*)(kbufA + swz(lr, cb + 64));
        short8 ktB8 = *(const short8*)(vbufB + swz(lr, cb + 64));
        short8 qtB8 = *(const short8*)(kbufB + swz(lr, cb + 64));
        short8 ktA = (g == 0) ? ktA8 : z8;   // zero-pad K=40 -> 32+8
        short8 qtA = (g == 0) ? qtA8 : z8;
        short8 ktB = (g == 0) ? ktB8 : z8;
        short8 qtB = (g == 0) ? qtB8 : z8;
        f32x4 cA = {0,0,0,0}, cB = {0,0,0,0};
        cA = __builtin_amdgcn_mfma_f32_16x16x32_bf16(kfA, qfA, cA, 0, 0, 0);
        cB = __builtin_amdgcn_mfma_f32_16x16x32_bf16(kfB, qfB, cB, 0, 0, 0);
        cA = __builtin_amdgcn_mfma_f32_16x16x32_bf16(ktA, qtA, cA, 0, 0, 0);
        cB = __builtin_amdgcn_mfma_f32_16x16x32_bf16(ktB, qtB, cB, 0, 0, 0);
        float svA[4], svB[4];
        float mA = -1e30f, mB = -1e30f;
#pragma unroll
        for (int r = 0; r < 4; ++r) {
            const bool ok = (g * 4 + r <= lr);
            svA[r] = ok ? cA[r] * scale : -1e30f;
            svB[r] = ok ? cB[r] * scale : -1e30f;
            mA = fmaxf(mA, svA[r]);
            mB = fmaxf(mB, svB[r]);
        }
        mA = fmaxf(mA, __shfl_xor(mA, 16));  mB = fmaxf(mB, __shfl_xor(mB, 16));
        mA = fmaxf(mA, __shfl_xor(mA, 32));  mB = fmaxf(mB, __shfl_xor(mB, 32));
        float sumA = 0.f, sumB = 0.f;
#pragma unroll
        for (int r = 0; r < 4; ++r) {
            svA[r] = __expf(svA[r] - mA);  sumA += svA[r];
            svB[r] = __expf(svB[r] - mB);  sumB += svB[r];
        }
        sumA += __shfl_xor(sumA, 16);  sumB += __shfl_xor(sumB, 16);
        sumA += __shfl_xor(sumA, 32);  sumB += __shfl_xor(sumB, 32);
        const float invA = 1.f / sumA, invB = 1.f / sumB;
        uint2v pkA, pkB;
        pkA[0] = (uint32_t)f2bf(svA[0] * invA) | ((uint32_t)f2bf(svA[1] * invA) << 16);
        pkA[1] = (uint32_t)f2bf(svA[2] * invA) | ((uint32_t)f2bf(svA[3] * invA) << 16);
        pkB[0] = (uint32_t)f2bf(svB[0] * invB) | ((uint32_t)f2bf(svB[1] * invB) << 16);
        pkB[1] = (uint32_t)f2bf(svB[2] * invB) | ((uint32_t)f2bf(svB[3] * invB) << 16);
        ppkA[h] = pkA;
        ppkB[h] = pkB;
    }

    proj(2, kbufA, kbufB, 1);   // V' (transposed [320][32B]) over Q

    // ---- PV via MFMA; attn-out -> vbuf (K dead); seqs interleaved ----
#pragma unroll
    for (int h = 0; h < 8; ++h) {
        short8 afA, afB;
        {
            uint2v own = ppkA[h];
            uint2v x16;
            x16[0] = (uint32_t)__shfl_xor((int)own[0], 16);
            x16[1] = (uint32_t)__shfl_xor((int)own[1], 16);
            uint4v pair;
            pair[0] = ((g & 1) == 0) ? own[0] : x16[0];
            pair[1] = ((g & 1) == 0) ? own[1] : x16[1];
            pair[2] = ((g & 1) == 0) ? x16[0] : own[0];
            pair[3] = ((g & 1) == 0) ? x16[1] : own[1];
            uint4v rec;
#pragma unroll
            for (int i = 0; i < 4; ++i) rec[i] = (uint32_t)__shfl_xor((int)pair[i], 32);
            uint4v af4;
#pragma unroll
            for (int i = 0; i < 4; ++i)
                af4[i] = (g == 0) ? pair[i] : (g == 1) ? rec[i] : 0u;
            afA = *(const short8*)&af4;
        }
        {
            uint2v own = ppkB[h];
            uint2v x16;
            x16[0] = (uint32_t)__shfl_xor((int)own[0], 16);
            x16[1] = (uint32_t)__shfl_xor((int)own[1], 16);
            uint4v pair;
            pair[0] = ((g & 1) == 0) ? own[0] : x16[0];
            pair[1] = ((g & 1) == 0) ? own[1] : x16[1];
            pair[2] = ((g & 1) == 0) ? x16[0] : own[0];
            pair[3] = ((g & 1) == 0) ? x16[1] : own[1];
            uint4v rec;
#pragma unroll
            for (int i = 0; i < 4; ++i) rec[i] = (uint32_t)__shfl_xor((int)pair[i], 32);
            uint4v af4;
#pragma unroll
            for (int i = 0; i < 4; ++i)
                af4[i] = (g == 0) ? pair[i] : (g == 1) ? rec[i] : 0u;
            afB = *(const short8*)&af4;
        }
#pragma unroll
        for (int t = 0; t < 3; ++t) {
            const int lcol = (t == 2) ? (lr & 7) : lr;
            const int col  = h * 40 + t * 16 + lcol;
            const short8 bfA = *(const short8*)(kbufA + col * 32 + g * 16);
            const short8 bfB = *(const short8*)(kbufB + col * 32 + g * 16);
            f32x4 oA = {0,0,0,0}, oB = {0,0,0,0};
            oA = __builtin_amdgcn_mfma_f32_16x16x32_bf16(afA, bfA, oA, 0, 0, 0);
            oB = __builtin_amdgcn_mfma_f32_16x16x32_bf16(afB, bfB, oB, 0, 0, 0);
            if (t < 2 || lr < 8) {
#pragma unroll
                for (int r = 0; r < 4; ++r) {
                    *(short*)(vbufA + swz(g * 4 + r, col * 2)) = (short)f2bf(oA[r]);
                    *(short*)(vbufB + swz(g * 4 + r, col * 2)) = (short)f2bf(oB[r]);
                }
            }
        }
    }

    // ---- output projection: shared Wo fragments, prefetch distance 2 ----
    short8 aofA[KS], aofB[KS];
#pragma unroll
    for (int ks = 0; ks < KS; ++ks) {
        aofA[ks] = *(const short8*)(vbufA + swz(lr, ks * 64 + g * 16));
        aofB[ks] = *(const short8*)(vbufB + swz(lr, ks * 64 + g * 16));
    }
    {
        const char* base = wpk + lane * 16 + (size_t)(3 * NT) * KS * 1024;
        short8 f0[KS], f1[KS], f2[KS], f3[KS];
#pragma unroll
        for (int ks = 0; ks < KS; ++ks) {
            f0[ks] = *(const short8*)(base + (size_t)ks * 1024);
            f1[ks] = *(const short8*)(base + (size_t)(KS + ks) * 1024);
        }
        auto outStore2 = [&](int t0, const f32x4& aA, const f32x4& bA,
                             const f32x4& aB, const f32x4& bB) {
            // tiles t0, t0+1 (t0 even): cols c0,c1 cover one 128B line per row
            const int c0 = t0 * 16 + lr;
            const int c1 = c0 + 16;
            const float bias0 = bo[c0];
            const float bias1 = bo[c1];
#pragma unroll
            for (int r = 0; r < 4; ++r) {
                float* rowpA = out + ((size_t)(bi * F + g * 4 + r) * DDIM + di) * CDIM;
                float* rowpB = rowpA + CDIM;
                rowpA[c0] = aA[r] + bias0;
                rowpA[c1] = bA[r] + bias1;
                rowpB[c0] = aB[r] + bias0;
                rowpB[c1] = bB[r] + bias1;
            }
        };
#pragma unroll 1
        for (int np2 = 0; np2 < 5; ++np2) {
            const int t = np2 * 4;
#pragma unroll
            for (int ks = 0; ks < KS; ++ks) {
                f2[ks] = *(const short8*)(base + (size_t)((t + 2) * KS + ks) * 1024);
                f3[ks] = *(const short8*)(base + (size_t)((t + 3) * KS + ks) * 1024);
            }
            {
                f32x4 a0A = {0,0,0,0}, a0B = {0,0,0,0}, a1A = {0,0,0,0}, a1B = {0,0,0,0};
#pragma unroll
                for (int ks = 0; ks < KS; ++ks) {
                    a0A = __builtin_amdgcn_mfma_f32_16x16x32_bf16(aofA[ks], f0[ks], a0A, 0, 0, 0);
                    a0B = __builtin_amdgcn_mfma_f32_16x16x32_bf16(aofB[ks], f0[ks], a0B, 0, 0, 0);
                    a1A = __builtin_amdgcn_mfma_f32_16x16x32_bf16(aofA[ks], f1[ks], a1A, 0, 0, 0);
                    a1B = __builtin_amdgcn_mfma_f32_16x16x32_bf16(aofB[ks], f1[ks], a1B, 0, 0, 0);
                }
                outStore2(t, a0A, a1A, a0B, a1B);
            }
            if (np2 < 4) {
#pragma unroll
                for (int ks = 0; ks < KS; ++ks) {
                    f0[ks] = *(const short8*)(base + (size_t)((t + 4) * KS + ks) * 1024);
                    f1[ks] = *(const short8*)(base + (size_t)((t + 5) * KS + ks) * 1024);
                }
            }
            {
                f32x4 a2A = {0,0,0,0}, a2B = {0,0,0,0}, a3A = {0,0,0,0}, a3B = {0,0,0,0};
#pragma unroll
                for (int ks = 0; ks < KS; ++ks) {
                    a2A = __builtin_amdgcn_mfma_f32_16x16x32_bf16(aofA[ks], f2[ks], a2A, 0, 0, 0);
                    a2B = __builtin_amdgcn_mfma_f32_16x16x32_bf16(aofB[ks], f2[ks], a2B, 0, 0, 0);
                    a3A = __builtin_amdgcn_mfma_f32_16x16x32_bf16(aofA[ks], f3[ks], a3A, 0, 0, 0);
                    a3B = __builtin_amdgcn_mfma_f32_16x16x32_bf16(aofB[ks], f3[ks], a3B, 0, 0, 0);
                }
                outStore2(t + 2, a2A, a3A, a2B, a3B);
            }
        }
    }
}

extern "C" void kernel_launch(void* const* d_in, const int* in_sizes, int n_in,
                              void* d_out, int out_size, void* d_ws, size_t ws_size,
                              hipStream_t stream) {
    const float* hs = (const float*)d_in[0];
    const float* Wq = (const float*)d_in[1];
    const float* Wk = (const float*)d_in[2];
    const float* Wv = (const float*)d_in[3];
    const float* Wo = (const float*)d_in[4];
    const float* bo = (const float*)d_in[5];
    float* out = (float*)d_out;
    char* wpk = (char*)d_ws;   // 4*200*1024 = 819200 B of packed bf16 weights

    pack_weights_kernel<<<dim3((4 * NT * KS * 64 + 255) / 256), dim3(256), 0, stream>>>(
        Wq, Wk, Wv, Wo, wpk);

    const int lds = 2 * 40960;   // 81920 B -> 2 blocks/CU (4 waves/CU)
    (void)hipFuncSetAttribute((const void*)temporal_attn_kernel,
                              hipFuncAttributeMaxDynamicSharedMemorySize, lds);
    temporal_attn_kernel<<<dim3(NSEQ / 4), dim3(THREADS), lds, stream>>>(
        hs, wpk, bo, out);
}